// Round 1
// baseline (181.678 us; speedup 1.0000x reference)
//
#include <hip/hip_runtime.h>
#include <cstdint>

#define FP8_MAX_F 448.0f

typedef float floatx4 __attribute__((ext_vector_type(4)));
typedef int   intx4   __attribute__((ext_vector_type(4)));
typedef int   intx8   __attribute__((ext_vector_type(8)));

static constexpr int Mdim = 2048;
static constexpr int Ndim = 4096;
static constexpr int Kdim = 4096;
static constexpr int BM = 128;
static constexpr int BN = 256;
static constexpr int BK = 128;   // fp8 bytes of K per staged tile
static constexpr int KT = Kdim / BK;  // 32 K-iterations

// amax: 8 float4 per thread, exact cover
static constexpr int A_XB = 1024;  // 2048*4096/4 / (256*8)
static constexpr int A_WB = 2048;  // 4096*4096/4 / (256*8)

__device__ __forceinline__ void async_load16(const void* g, void* l) {
  __builtin_amdgcn_global_load_lds((__attribute__((address_space(1))) void*)g,
                                   (__attribute__((address_space(3))) void*)l,
                                   16, 0, 0);
}

// ---------------------------------------------------------------------------
// Pass 1: per-block partial abs-max, both tensors in one dispatch.
// 8 independent float4 loads/thread; per-block partial slot (no atomics).
// ---------------------------------------------------------------------------
__global__ void amax_partials(const float* __restrict__ x,
                              const float* __restrict__ w,
                              float* __restrict__ part) {
  const int b = blockIdx.x;
  const float4* p4;
  float* dst;
  int bid;
  if (b < A_XB) { p4 = (const float4*)x; dst = part;        bid = b; }
  else          { p4 = (const float4*)w; dst = part + A_XB; bid = b - A_XB; }
  const int tid = threadIdx.x;
  const int base = bid * 2048 + tid;
  float4 v[8];
#pragma unroll
  for (int u = 0; u < 8; u++) v[u] = p4[base + u * 256];
  float m = 0.f;
#pragma unroll
  for (int u = 0; u < 8; u++)
    m = fmaxf(m, fmaxf(fmaxf(fabsf(v[u].x), fabsf(v[u].y)),
                       fmaxf(fabsf(v[u].z), fabsf(v[u].w))));
#pragma unroll
  for (int off = 32; off > 0; off >>= 1)
    m = fmaxf(m, __shfl_down(m, off, 64));
  __shared__ float red[4];
  if ((tid & 63) == 0) red[tid >> 6] = m;
  __syncthreads();
  if (tid == 0)
    dst[bid] = fmaxf(fmaxf(red[0], red[1]), fmaxf(red[2], red[3]));
}

// ---------------------------------------------------------------------------
// Pass 2: reduce partials -> per-tensor amax (block 0 of each tensor also
// publishes the scalar for the gemm epilogue), then quantize fp32 -> fp8
// e4m3fn. 3072 blocks, 8 float4/thread (was 6144x4) — halves the per-block
// partial-reduce preambles. Mirrors reference fp32 arithmetic exactly.
// ---------------------------------------------------------------------------
__global__ void quant_both(const float* __restrict__ x,
                           const float* __restrict__ w,
                           const float* __restrict__ part,
                           unsigned int* __restrict__ qx,
                           unsigned int* __restrict__ qw,
                           float* __restrict__ scalars) {
  const int b = blockIdx.x;
  const float4* p4;
  const float* po;
  unsigned int* q;
  float* slot;
  int np, bid;
  if (b < A_XB) { p4 = (const float4*)x; po = part;        q = qx; np = A_XB; bid = b;        slot = scalars;     }
  else          { p4 = (const float4*)w; po = part + A_XB; q = qw; np = A_WB; bid = b - A_XB; slot = scalars + 1; }
  const int tid = threadIdx.x;

  float m = 0.f;
  for (int i = tid; i < np; i += 256) m = fmaxf(m, po[i]);
#pragma unroll
  for (int off = 32; off > 0; off >>= 1)
    m = fmaxf(m, __shfl_down(m, off, 64));
  __shared__ float red[4];
  __shared__ float amax_s;
  if ((tid & 63) == 0) red[tid >> 6] = m;
  __syncthreads();
  if (tid == 0) {
    float mm = fmaxf(fmaxf(fmaxf(red[0], red[1]), fmaxf(red[2], red[3])), 1e-12f);
    amax_s = mm;
    if (bid == 0) *slot = mm;
  }
  __syncthreads();
  const float scale = FP8_MAX_F / amax_s;

  const int base = bid * 2048 + tid;
#pragma unroll
  for (int u = 0; u < 8; u++) {
    float4 v = p4[base + u * 256];
    float a = fminf(fmaxf(v.x * scale, -FP8_MAX_F), FP8_MAX_F);
    float bb = fminf(fmaxf(v.y * scale, -FP8_MAX_F), FP8_MAX_F);
    float c = fminf(fmaxf(v.z * scale, -FP8_MAX_F), FP8_MAX_F);
    float d = fminf(fmaxf(v.w * scale, -FP8_MAX_F), FP8_MAX_F);
    unsigned int r = 0;
    r = __builtin_amdgcn_cvt_pk_fp8_f32(a, bb, r, false);
    r = __builtin_amdgcn_cvt_pk_fp8_f32(c, d, r, true);
    q[base + u * 256] = r;
  }
}

// ---------------------------------------------------------------------------
// FP8 GEMM (mfma_scale_f32_16x16x128_f8f6f4, unit e8m0 scales = plain fp8
// dot + fp32 acc). R5: LDS-bandwidth attack. The 64x32-per-wave version was
// LDS-read-bound (42.7 MFMA-FLOP per LDS byte vs the ~89 needed to saturate
// the MX pipe at 85 B/cyc). This version: 128x256 block tile, 8 waves in a
// 2Mx4N grid, each wave a 64x64 C-tile (acc[4][4]) -> 64 FLOP/B, cutting
// per-CU LDS traffic per K-step from 256 KB to 176 KB while keeping the MFMA
// work identical. 96 KiB LDS, 1 block/CU, all 256 blocks co-resident.
//
// XCD swizzle: 16x16 block grid, each XCD owns a 4M x 8N sub-grid, so the
// 8-way A-panel reuse and 4-way B-panel reuse resolve in the XCD-local L2
// (phase-aligned since every block starts kt simultaneously).
//
// Single-barrier double-buffered pipeline (proven in R4): per K-iter
// [barrier drains loads issued LAST iter] [issue 6 async16 for tile k+1]
// [compute tile k]. LDS rows of 128B = 8 chunks of 16B, XOR-swizzled:
// logical chunk c of row r at physical chunk c ^ (r&7); staging pins LDS dst
// to tid*16 and pre-swizzles the global source column.
// Fragment layouts (HW-verified m89/m148): A: lane holds
// A[m=lane&15][k=(lane>>4)*32 + j], j=0..31; C/D: col=lane&15,
// row=(lane>>4)*4+reg.
// ---------------------------------------------------------------------------
__launch_bounds__(512, 2)
__global__ void gemm_fp8(const unsigned char* __restrict__ qx,
                         const unsigned char* __restrict__ qw,
                         const float* __restrict__ bias,
                         const float* __restrict__ scalars,
                         float* __restrict__ out) {
  __shared__ __align__(16) unsigned char As[2 * BM * BK];  // 2 x 16 KiB
  __shared__ __align__(16) unsigned char Bs[2 * BN * BK];  // 2 x 32 KiB

  const int tid = threadIdx.x;   // 0..511
  const int lane = tid & 63;
  const int wv = tid >> 6;       // 0..7
  const int wm = (wv & 1) * 64;  // wave M offset (2 rows of waves)
  const int wn = (wv >> 1) * 64; // wave N offset (4 cols of waves)

  // XCD-aware 2D swizzle: bid%8 = XCD; each XCD gets a 4(M) x 8(N) sub-grid.
  const int bid = blockIdx.x;            // 0..255
  const int xcd = bid & 7;
  const int idx = bid >> 3;              // 0..31
  const int by = (xcd >> 1) * 4 + (idx & 3);   // 0..15
  const int bx = (xcd & 1) * 8 + (idx >> 2);   // 0..15
  const int bm0 = by * BM;
  const int bn0 = bx * BN;

  // Staging source map: 6 async16 per thread per tile (A: 2 rounds of 64
  // rows, B: 4 rounds of 64 rows), LDS dst pinned to tid*16 per 8KB round.
  const int srow = tid >> 3;                          // 0..63
  const int sc = ((tid & 7) ^ ((tid >> 3) & 7)) << 4; // swizzled source col
  const unsigned char* gA0 = qx + (size_t)(bm0 + srow) * Kdim + sc;
  const unsigned char* gB0 = qw + (size_t)(bn0 + srow) * Kdim + sc;
  const size_t rstep = (size_t)64 * Kdim;
  const int lslot = tid * 16;

  floatx4 acc[4][4];
#pragma unroll
  for (int i = 0; i < 4; i++)
#pragma unroll
    for (int j = 0; j < 4; j++) acc[i][j] = (floatx4){0.f, 0.f, 0.f, 0.f};

  // Fragment read constants
  const int frow = lane & 15;
  const int h = lane >> 4;                   // k-block 0..3 (32B each)
  const int fr7 = frow & 7;
  const int kc0 = ((2 * h) ^ fr7) << 4;      // phys offset of logical chunk 2h
  const int kc1 = ((2 * h + 1) ^ fr7) << 4;  // phys offset of chunk 2h+1

  // Prologue: stage tile 0 into buffer 0
  async_load16(gA0, As + lslot);
  async_load16(gA0 + rstep, As + 8192 + lslot);
  async_load16(gB0, Bs + lslot);
  async_load16(gB0 + rstep, Bs + 8192 + lslot);
  async_load16(gB0 + 2 * rstep, Bs + 16384 + lslot);
  async_load16(gB0 + 3 * rstep, Bs + 24576 + lslot);

  for (int kt = 0; kt < KT; ++kt) {
    __syncthreads();  // drains loads issued LAST iter (a full compute ago)
    const int abuf = (kt & 1) * 16384;
    const int bbuf = (kt & 1) * 32768;
    if (kt + 1 < KT) {
      const int anb = ((kt + 1) & 1) * 16384;
      const int bnb = ((kt + 1) & 1) * 32768;
      const int k0 = (kt + 1) * BK;
      async_load16(gA0 + k0, As + anb + lslot);
      async_load16(gA0 + k0 + rstep, As + anb + 8192 + lslot);
      async_load16(gB0 + k0, Bs + bnb + lslot);
      async_load16(gB0 + k0 + rstep, Bs + bnb + 8192 + lslot);
      async_load16(gB0 + k0 + 2 * rstep, Bs + bnb + 16384 + lslot);
      async_load16(gB0 + k0 + 3 * rstep, Bs + bnb + 24576 + lslot);
    }

    intx8 af[4], bf[4];
#pragma unroll
    for (int t = 0; t < 4; t++) {
      const unsigned char* ra = As + abuf + (wm + t * 16 + frow) * BK;
      intx4 lo = *(const intx4*)(ra + kc0);
      intx4 hi = *(const intx4*)(ra + kc1);
      af[t] = __builtin_shufflevector(lo, hi, 0, 1, 2, 3, 4, 5, 6, 7);
    }
#pragma unroll
    for (int u = 0; u < 4; u++) {
      const unsigned char* rb = Bs + bbuf + (wn + u * 16 + frow) * BK;
      intx4 lo = *(const intx4*)(rb + kc0);
      intx4 hi = *(const intx4*)(rb + kc1);
      bf[u] = __builtin_shufflevector(lo, hi, 0, 1, 2, 3, 4, 5, 6, 7);
    }
#pragma unroll
    for (int i = 0; i < 4; i++)
#pragma unroll
      for (int j = 0; j < 4; j++)
        acc[i][j] = __builtin_amdgcn_mfma_scale_f32_16x16x128_f8f6f4(
            af[i], bf[j], acc[i][j], 0 /*A=fp8*/, 0 /*B=fp8*/,
            0, 0x7F7F7F7F, 0, 0x7F7F7F7F);  // unit scales (e8m0 127 = 2^0)
  }

  // Dequant scale, mirroring reference fp32 arithmetic exactly.
  float ax = fmaxf(scalars[0], 1e-12f);
  float aw = fmaxf(scalars[1], 1e-12f);
  float cs = (1.0f / (FP8_MAX_F / ax)) * (1.0f / (FP8_MAX_F / aw));

  const int crow = bm0 + wm + (lane >> 4) * 4;
  const int ccol = bn0 + wn + (lane & 15);
#pragma unroll
  for (int j = 0; j < 4; j++) {
    float bv = bias[ccol + j * 16];
#pragma unroll
    for (int i = 0; i < 4; i++) {
#pragma unroll
      for (int r = 0; r < 4; r++) {
        out[(size_t)(crow + i * 16 + r) * Ndim + (ccol + j * 16)] =
            acc[i][j][r] * cs + bv;
      }
    }
  }
}

extern "C" void kernel_launch(void* const* d_in, const int* in_sizes, int n_in,
                              void* d_out, int out_size, void* d_ws, size_t ws_size,
                              hipStream_t stream) {
  const float* x = (const float*)d_in[0];     // [M,K] fp32
  const float* w = (const float*)d_in[1];     // [N,K] fp32
  const float* bias = (const float*)d_in[2];  // [N] fp32
  float* out = (float*)d_out;                 // [M,N] fp32

  // Workspace: partials (3072 f) | scalars (2 f) | pad to 32 KiB | qx | qw
  float* part = (float*)d_ws;
  float* scalars = part + 4096;
  unsigned char* qx = (unsigned char*)d_ws + 32768;
  unsigned char* qw = qx + (size_t)Mdim * Kdim;

  amax_partials<<<A_XB + A_WB, 256, 0, stream>>>(x, w, part);
  quant_both<<<A_XB + A_WB, 256, 0, stream>>>(x, w, part,
                                              (unsigned int*)qx, (unsigned int*)qw,
                                              scalars);
  gemm_fp8<<<256, 512, 0, stream>>>(qx, qw, bias, scalars, out);
}